// Round 1
// baseline (118.304 us; speedup 1.0000x reference)
//
#include <hip/hip_runtime.h>
#include <math.h>

// DetectionLayer (YOLO-style head) for x:(32,255,76,76) f32 -> out:(32,17328,85) f32
// B=32, bpc=3 anchors, num_attrs=85, H=W=76, HW=5776.
//
// Strategy: block = (b, anchor a, grid row i). LDS tile-transpose:
//   load 85 channels x 76 cols (coalesced 304B runs per channel),
//   write 76 rows x 85 attrs (contiguous 340B runs, dense output region).

#define BATCH      32
#define NCH        255
#define NATTR      85
#define BPC        3
#define GW         76
#define GH         76
#define HW         (GW * GH)          // 5776
#define PAD        77                 // odd pad -> conflict-free strided LDS reads
#define NELEM      (NATTR * GW)       // 6460 per block
#define BLOCK      256

__global__ __launch_bounds__(BLOCK) void det_layer_kernel(
        const float* __restrict__ in, float* __restrict__ out) {
    // decompose block id: bid = (b*BPC + a)*GH + i
    int bid = blockIdx.x;
    int i   = bid % GH;
    int ba  = bid / GH;
    int a   = ba % BPC;
    int b   = ba / BPC;

    __shared__ float lds[NATTR * PAD];

    // ---- load phase: 85 channels x 76 cols ----
    const float* __restrict__ src =
        in + ((size_t)(b * NCH + a * NATTR) * HW + (size_t)i * GW);
    #pragma unroll 4
    for (int e = threadIdx.x; e < NELEM; e += BLOCK) {
        int c = e / GW;          // channel (attr) 0..84
        int j = e - c * GW;      // col 0..75
        lds[c * PAD + j] = src[(size_t)c * HW + j];
    }
    __syncthreads();

    // ---- compute + write phase: 76 rows x 85 attrs ----
    const float aw[3] = {10.f, 16.f, 33.f};
    const float ah[3] = {13.f, 30.f, 23.f};
    const float anchor_w = aw[a] * (0.5f / 608.0f);   // pre-fold *0.5/image_size
    const float anchor_h = ah[a] * (0.5f / 608.0f);
    const float inv_grid = 1.0f / 76.0f;
    const float gy = (float)i;

    float* __restrict__ dst =
        out + ((size_t)b * (HW * BPC) + (size_t)i * (GW * BPC) + a) * NATTR;

    #pragma unroll 4
    for (int e = threadIdx.x; e < NELEM; e += BLOCK) {
        int j = e / NATTR;       // col 0..75
        int t = e - j * NATTR;   // attr 0..84
        float val;
        if (t >= 4) {
            // confidence + class probs: plain sigmoid
            float v = lds[t * PAD + j];
            val = 1.0f / (1.0f + __expf(-v));
        } else {
            float a0 = lds[0 * PAD + j];
            float a1 = lds[1 * PAD + j];
            float a2 = lds[2 * PAD + j];
            float a3 = lds[3 * PAD + j];
            float bx = (1.0f / (1.0f + __expf(-a0))) * 1.05f - 0.025f;
            float by = (1.0f / (1.0f + __expf(-a1))) * 1.05f - 0.025f;
            float ix = (bx + (float)j) * inv_grid;
            float iy = (by + gy) * inv_grid;
            float hw2 = __expf(a2) * anchor_w;   // half width
            float hh2 = __expf(a3) * anchor_h;   // half height
            val = (t == 0) ? (ix - hw2)
                : (t == 1) ? (iy - hh2)
                : (t == 2) ? (ix + hw2)
                :            (iy + hh2);
        }
        dst[(size_t)j * (BPC * NATTR) + t] = val;
    }
}

extern "C" void kernel_launch(void* const* d_in, const int* in_sizes, int n_in,
                              void* d_out, int out_size, void* d_ws, size_t ws_size,
                              hipStream_t stream) {
    const float* x = (const float*)d_in[0];
    float* out = (float*)d_out;
    int grid = BATCH * BPC * GH;   // 32*3*76 = 7296 blocks
    det_layer_kernel<<<grid, BLOCK, 0, stream>>>(x, out);
}

// Round 2
// 92.878 us; speedup vs baseline: 1.2737x; 1.2737x over previous
//
#include <hip/hip_runtime.h>
#include <math.h>

// DetectionLayer: x(32,255,76,76) f32 -> out(32,17328,85) f32
// Block = (b, grid-row i, j-half). Phase 1: float4-coalesced load of the
// 255ch x (40|36)col input slab into LDS [c][PADJ=41] (stride 41 is odd and
// 41%32=9 coprime -> conflict-free strided reads). Phase 2: row-per-wave,
// lane = attr t; all index math wave-uniform, stores wave-coalesced.
// Corners (t<4) handled branchlessly via one shared __expf + shfl_xor(.,2).

#define NCH   255
#define NATTR 85
#define HW    5776
#define GW    76
#define NBATCH 32
#define PADJ  41
#define BLOCK 512
#define NWAVE (BLOCK / 64)

__global__ __launch_bounds__(BLOCK) void det_kernel(const float* __restrict__ in,
                                                    float* __restrict__ out) {
    const int bid = blockIdx.x;
    const int jh  = bid & 1;          // which j-half: 0 -> j[0,40), 1 -> j[40,76)
    const int bi  = bid >> 1;
    const int i   = bi % GW;
    const int b   = bi / GW;
    const int j0    = jh ? 40 : 0;
    const int nrows = jh ? (3 * 36) : (3 * 40);

    __shared__ float lds[NCH * PADJ];

    const float* __restrict__ src =
        in + (size_t)b * (NCH * HW) + (size_t)i * GW + j0;

    // ---- phase 1: float4 loads, coalesced along j ----
    if (jh == 0) {
        #pragma unroll 2
        for (int e = threadIdx.x; e < NCH * 10; e += BLOCK) {
            int c = e / 10;
            int q = e - c * 10;
            float4 v = *(const float4*)(src + (size_t)c * HW + 4 * q);
            float* p = &lds[c * PADJ + 4 * q];
            p[0] = v.x; p[1] = v.y; p[2] = v.z; p[3] = v.w;
        }
    } else {
        #pragma unroll 2
        for (int e = threadIdx.x; e < NCH * 9; e += BLOCK) {
            int c = e / 9;
            int q = e - c * 9;
            float4 v = *(const float4*)(src + (size_t)c * HW + 4 * q);
            float* p = &lds[c * PADJ + 4 * q];
            p[0] = v.x; p[1] = v.y; p[2] = v.z; p[3] = v.w;
        }
    }
    __syncthreads();

    // ---- phase 2: one output row (85 attrs) per wave, lane = t ----
    const int wv = threadIdx.x >> 6;
    const int t  = threadIdx.x & 63;
    float* __restrict__ dst =
        out + ((size_t)b * 17328 + (size_t)(i * GW + j0) * 3) * NATTR;
    const float fi = (float)i;

    for (int r = wv; r < nrows; r += NWAVE) {
        int jj = r / 3;                 // local col
        int a  = r - 3 * jj;            // anchor
        const int j = j0 + jj;
        const float anc_w = ((a == 0) ? 10.f : (a == 1) ? 16.f : 33.f) * (0.5f / 608.f);
        const float anc_h = ((a == 0) ? 13.f : (a == 1) ? 30.f : 23.f) * (0.5f / 608.f);
        const float* rowp = &lds[(a * NATTR) * PADJ + jj];

        float v = rowp[t * PADJ];
        bool iswh = ((t | 1) == 3);               // t==2 || t==3
        float m = iswh ? v : -v;
        float E = __expf(m);
        float s = 1.0f / (1.0f + E);              // sigmoid for non-wh lanes
        // corner prep (only meaningful for t<4):
        //  t0: ix = (sig*1.05-0.025 + j)/76     t2: hw2 = exp(v)*aw*0.5/608
        //  t1: iy = (sig*1.05-0.025 + i)/76     t3: hh2 = exp(v)*ah*0.5/608
        float coord = (t & 1) ? fi : (float)j;
        float anc   = (t & 1) ? anc_h : anc_w;
        float tmp = (t < 2) ? ((s * 1.05f - 0.025f + coord) * (1.0f / 76.0f))
                            : (E * anc);
        float pp = __shfl_xor(tmp, 2);            // lane t <-> t^2: ix<->hw2, iy<->hh2
        float cv = (t < 2) ? (tmp - pp) : (tmp + pp);
        float val = (t < 4) ? cv : s;

        size_t o = (size_t)r * NATTR + t;
        dst[o] = val;
        if (t < NATTR - 64) {                     // attrs 64..84 (never corners)
            float v2 = rowp[(t + 64) * PADJ];
            dst[o + 64] = 1.0f / (1.0f + __expf(-v2));
        }
    }
}

extern "C" void kernel_launch(void* const* d_in, const int* in_sizes, int n_in,
                              void* d_out, int out_size, void* d_ws, size_t ws_size,
                              hipStream_t stream) {
    const float* x = (const float*)d_in[0];
    float* out = (float*)d_out;
    int grid = NBATCH * GW * 2;    // 32*76*2 = 4864 blocks
    det_kernel<<<grid, BLOCK, 0, stream>>>(x, out);
}